// Round 4
// baseline (266.354 us; speedup 1.0000x reference)
//
#include <hip/hip_runtime.h>

// LRN (buggy-keras window) on x:(64,56,56,192) fp32 NHWC.
// window for channel c: [max(c-2,0), min(2c+3, C)); scale=(sum*2e-5+1)^0.75; out=x/scale
//
// R7: TRUE persistence. R6 was confounded: GRID=1792 (needs 7 blocks/CU) with
// __launch_bounds__(256,4) caps residency at 4 blocks/CU -> 768 blocks ran as a
// staggered 2nd round; occupancy FELL to 55% and time got slightly worse (exactly
// what the duty-cycle theory predicts for fewer resident waves). Fix: bounds (256,8)
// -> capacity 8 blocks/CU >= 7 needed -> all 1792 blocks co-resident, 28 waves/CU,
// zero churn; 50176 groups / 7168 slots = exactly 7 iters/slot, zero tail.
// Depth-1 register prefetch keeps ~3KB outstanding per wave continuously
// (~84KB/CU >> ~10KB Little's-law need for 6.3 TB/s).
// Body = R5/R6 (interleaved ownership, 3x16-wide scan, 12 bpermute gather, NT stores).
// (1+e)^-0.75 via cubic series (e<=~0.01 -> err <1e-7 vs thr 0.108).

constexpr int   C     = 192;
constexpr int   LPP   = 16;             // lanes per pixel
constexpr int   PPW   = 4;              // pixels per wave per iteration
constexpr int   WPB   = 4;              // waves per block
constexpr int   BLOCK = 256;
constexpr int   GRID  = 1792;           // 7168 wave-slots; 7 blocks/CU, all resident
constexpr float AON   = 0.0001f / 5.0f; // alpha/n = 2e-5

typedef float f32x4 __attribute__((ext_vector_type(4)));

__device__ __forceinline__ float bperm(int byteaddr, float v) {
  return __int_as_float(__builtin_amdgcn_ds_bpermute(byteaddr, __float_as_int(v)));
}

__device__ __forceinline__ void nt_store4(float a, float b, float c, float d,
                                          float4* __restrict__ p) {
  f32x4 t = {a, b, c, d};
  __builtin_nontemporal_store(t, (f32x4*)p);
}

// Compute + store one pixel-iteration from registers. u0/u1/u2 = float4s {sub,16+sub,32+sub}
// of this lane's pixel row; ob = pixel row base (float4*); a0/a1/a2 = bpermute byte addrs.
__device__ __forceinline__ void lrn_body(const float4 u0, const float4 u1, const float4 u2,
                                         float4* __restrict__ ob, int sub,
                                         int a0, int a1, int a2) {
  float xs[3][4] = {{u0.x, u0.y, u0.z, u0.w},
                    {u1.x, u1.y, u1.z, u1.w},
                    {u2.x, u2.y, u2.z, u2.w}};

  // ---- chunk sums q[s] over slot s (chunk index m = 16s + sub) ----
  float q[3];
#pragma unroll
  for (int s = 0; s < 3; ++s)
    q[s] = fmaf(xs[s][0], xs[s][0],
           fmaf(xs[s][1], xs[s][1],
           fmaf(xs[s][2], xs[s][2], xs[s][3] * xs[s][3])));

  // ---- three independent 16-wide inclusive scans ----
  float i0 = q[0], i1 = q[1], i2 = q[2];
#pragma unroll
  for (int off = 1; off < LPP; off <<= 1) {
    const float t0 = __shfl_up(i0, off, LPP);
    const float t1 = __shfl_up(i1, off, LPP);
    const float t2 = __shfl_up(i2, off, LPP);
    if (sub >= off) { i0 += t0; i1 += t1; i2 += t2; }
  }
  const float T0 = __shfl(i0, LPP - 1, LPP);
  const float T1 = __shfl(i1, LPP - 1, LPP);
  const float T2 = __shfl(i2, LPP - 1, LPP);
  const float total = T0 + T1 + T2;                    // cs[192]
  const float E[3] = { i0 - q[0], T0 + i1 - q[1], T0 + T1 + i2 - q[2] };

  // ---- per-slot channel prefixes: p[s][k] = cs[64s + 4sub + k] ----
  float p[3][4];
#pragma unroll
  for (int s = 0; s < 3; ++s) {
    float run = E[s];
#pragma unroll
    for (int k = 0; k < 4; ++k) { p[s][k] = run; run = fmaf(xs[s][k], xs[s][k], run); }
  }

  // ---- head boundaries: hb0[s]=cs[64s+4sub-2], hb1[s]=cs[64s+4sub-1] ----
  float hb0[3], hb1[3];
#pragma unroll
  for (int s = 0; s < 3; ++s) {
    hb0[s] = __shfl_up(p[s][2], 1, LPP);
    hb1[s] = __shfl_up(p[s][3], 1, LPP);
  }
  const float B02 = __shfl(p[0][2], LPP - 1, LPP);   // cs[62]
  const float B03 = __shfl(p[0][3], LPP - 1, LPP);   // cs[63]
  const float B12 = __shfl(p[1][2], LPP - 1, LPP);   // cs[126]
  const float B13 = __shfl(p[1][3], LPP - 1, LPP);   // cs[127]
  if (sub == 0) {
    hb0[0] = 0.0f; hb1[0] = 0.0f;
    hb0[1] = B02;  hb1[1] = B03;
    hb0[2] = B12;  hb1[2] = B13;
  }

  // ---- gather cs[end], end = 2c+3 = 128s + 8sub + 2k + 3 (valid iff c <= 94) ----
  float ge0[4], ge1[4];
  {
    const float r00 = bperm(a0, p[0][3]), r01 = bperm(a0, p[1][3]);  // k=0
    const float r10 = bperm(a1, p[0][1]), r11 = bperm(a1, p[1][1]);  // k=1
    const float r20 = bperm(a1, p[0][3]), r21 = bperm(a1, p[1][3]);  // k=2
    const float r30 = bperm(a2, p[0][1]), r31 = bperm(a2, p[1][1]);  // k=3
    ge0[0] = (sub < 8) ? r00 : r01;
    ge0[1] = (sub < 8) ? r10 : r11;
    ge0[2] = (sub < 8) ? r20 : r21;
    ge0[3] = (sub < 7) ? r30 : r31;
    ge1[0] = bperm(a0, p[2][3]);
    ge1[1] = bperm(a1, p[2][1]);
    ge1[2] = bperm(a1, p[2][3]);
    ge1[3] = bperm(a2, p[2][1]);
  }

  // ---- windowed sums + series scale + coalesced NT stores ----
#pragma unroll
  for (int s = 0; s < 3; ++s) {
    float r[4];
#pragma unroll
    for (int k = 0; k < 4; ++k) {
      const float csh = (k >= 2) ? p[s][k - 2] : (k == 0 ? hb0[s] : hb1[s]);
      float cse;
      if (s == 0)      cse = ge0[k];
      else if (s == 1) cse = (4 * sub + k >= 31) ? total : ge1[k];
      else             cse = total;
      const float eps = (cse - csh) * AON;        // in [0, ~0.01]
      // (1+e)^-0.75 ~= 1 - 0.75e + 0.65625e^2 - 0.6015625e^3
      const float inv = fmaf(eps, fmaf(eps, fmaf(eps, -0.6015625f, 0.65625f), -0.75f), 1.0f);
      r[k] = xs[s][k] * inv;
    }
    nt_store4(r[0], r[1], r[2], r[3], &ob[16 * s + sub]);
  }
}

__global__ __launch_bounds__(BLOCK, 8) void lrn_kernel(
    const float* __restrict__ x, float* __restrict__ out, int npix) {
  const int tid  = threadIdx.x;
  const int lane = tid & 63;
  const int w    = tid >> 6;
  const int sub  = lane & 15;   // lane within pixel
  const int pl   = lane >> 4;   // pixel within wave

  const int slot   = blockIdx.x * WPB + w;   // wave-slot id
  const int nslots = gridDim.x * WPB;        // 7168
  const int ngrp   = (npix + PPW - 1) / PPW; // pixel-groups (50176)
  int nit = (ngrp - slot + nslots - 1) / nslots;   // exactly 7 for this shape
  if (nit <= 0) return;

  // bpermute byte addresses (lane-only; hoisted out of the loop)
  const int gb = lane & 48;
  const int a0 = (gb | ((2 * sub)     & 15)) << 2;
  const int a1 = (gb | ((2 * sub + 1) & 15)) << 2;
  const int a2 = (gb | ((2 * sub + 2) & 15)) << 2;

  const float4* __restrict__ xb = (const float4*)x;
  const int nclamp = npix - 1;

  int grp = slot;
  int pix = grp * PPW + pl; if (pix > nclamp) pix = nclamp;
  int fb  = pix * (C / 4) + sub;             // float4 index of slot-0 quad
  float4 A0 = xb[fb], A1 = xb[fb + 16], A2 = xb[fb + 32];

  for (int t = 0; t < nit; ++t) {
    const int curfb = fb;                    // output base = input base (same layout)
    const int gn = grp + nslots;
    float4 B0, B1, B2;
    if (t + 1 < nit) {                       // slot-uniform branch
      int pixn = gn * PPW + pl; if (pixn > nclamp) pixn = nclamp;
      fb = pixn * (C / 4) + sub;
      B0 = xb[fb]; B1 = xb[fb + 16]; B2 = xb[fb + 32];   // issue next loads FIRST
    }
    float4* ob = (float4*)out + (curfb - sub);           // pixel row base
    lrn_body(A0, A1, A2, ob, sub, a0, a1, a2);
    grp = gn;
    A0 = B0; A1 = B1; A2 = B2;
  }
}

extern "C" void kernel_launch(void* const* d_in, const int* in_sizes, int n_in,
                              void* d_out, int out_size, void* d_ws, size_t ws_size,
                              hipStream_t stream) {
  const float* x   = (const float*)d_in[0];
  float*       out = (float*)d_out;
  const int npix = in_sizes[0] / C;                  // 64*56*56 = 200704
  const int ngrp = (npix + PPW - 1) / PPW;           // 50176
  int grid = (ngrp + WPB - 1) / WPB;                 // cap for tiny inputs
  if (grid > GRID) grid = GRID;                      // 1792 -> 7168 slots, 7 iters each
  lrn_kernel<<<grid, BLOCK, 0, stream>>>(x, out, npix);
}

// Round 6
// 264.686 us; speedup vs baseline: 1.0063x; 1.0063x over previous
//
#include <hip/hip_runtime.h>

// LRN (buggy-keras window) on x:(64,56,56,192) fp32 NHWC.
// window for channel c: [max(c-2,0), min(2c+3, C)); scale=(sum*2e-5+1)^0.75; out=x/scale
//
// R9 = R8 (forced prefetch) minus the register-copy race.
// Evidence driving this: VGPR_Count=32 in R4/R6/R7 proves the compiler sank every
// source-level prefetch load to its first use -> all prior rounds ran the same serial
// load->wait->scan->store schedule (iter time ~32k cycles vs ~600-cycle body).
// Fix: issue loads via inline-asm global_load_dwordx4 (opaque, unsinkable), consume
// after a counted s_waitcnt + sched_barrier(0) (rule #18). R8's bug: `A0 = B0` copied
// dest regs of still-outstanding loads (no VMEM scoreboard on CDNA -> race). R9 uses
// unroll-by-2 with two fixed buffer sets and NO copies: peel {issue B, vmcnt(3),
// body A}; pairs {issue A', vmcnt(6), body B} / {issue B', vmcnt(6), body A}; vmcnt(6)
// = 3 just-issued loads + <=3 own stores from the PREVIOUS body -> waits exactly the
// loads issued one body earlier, never the just-issued stores.
// GRID=1536 @ launch_bounds(256,6): 6 blocks/CU x 256 CU = all resident, zero churn.
// Body = R5 (interleaved ownership, 3x16-wide scan, 12 bpermute gather, NT stores);
// (1+e)^-0.75 via cubic series (e<=~0.01 -> err <1e-7 vs thr 0.108).

constexpr int   C     = 192;
constexpr int   LPP   = 16;             // lanes per pixel
constexpr int   PPW   = 4;              // pixels per wave per iteration
constexpr int   WPB   = 4;              // waves per block
constexpr int   BLOCK = 256;
constexpr int   GRID  = 1536;           // 6144 wave-slots; all resident at 6 blocks/CU
constexpr float AON   = 0.0001f / 5.0f; // alpha/n = 2e-5

typedef float f32x4 __attribute__((ext_vector_type(4)));

__device__ __forceinline__ float bperm(int byteaddr, float v) {
  return __int_as_float(__builtin_amdgcn_ds_bpermute(byteaddr, __float_as_int(v)));
}

__device__ __forceinline__ void nt_store4(float a, float b, float c, float d,
                                          float4* __restrict__ p) {
  f32x4 t = {a, b, c, d};
  __builtin_nontemporal_store(t, (f32x4*)p);
}

// Issue 3 coalesced dwordx4 loads (bytes +0/+256/+512 from p) WITHOUT waiting.
// Opaque to the compiler: cannot be sunk to first use. "memory" pins ordering vs the
// NT stores so the manual vmcnt accounting stays exact.
__device__ __forceinline__ void issue3(const float* p, f32x4& d0, f32x4& d1, f32x4& d2) {
  asm volatile(
      "global_load_dwordx4 %0, %3, off\n\t"
      "global_load_dwordx4 %1, %3, off offset:256\n\t"
      "global_load_dwordx4 %2, %3, off offset:512"
      : "=&v"(d0), "=&v"(d1), "=&v"(d2)
      : "v"(p)
      : "memory");
}

__device__ __forceinline__ int fb_of(int g, int pl, int sub, int nclamp) {
  int p = g * PPW + pl;
  if (p > nclamp) p = nclamp;     // benign clamp: duplicate loads, never processed twice
  return p * (C / 4) + sub;       // float4 index of this lane's slot-0 quad
}

// Compute + store one pixel-iteration from registers. u0/u1/u2 = float4s {sub,16+sub,32+sub}
// of this lane's pixel row; ob = pixel row base (float4*); a0/a1/a2 = bpermute byte addrs.
__device__ __forceinline__ void lrn_body(const f32x4 u0, const f32x4 u1, const f32x4 u2,
                                         float4* __restrict__ ob, int sub,
                                         int a0, int a1, int a2) {
  float xs[3][4] = {{u0.x, u0.y, u0.z, u0.w},
                    {u1.x, u1.y, u1.z, u1.w},
                    {u2.x, u2.y, u2.z, u2.w}};

  // ---- chunk sums q[s] over slot s (chunk index m = 16s + sub) ----
  float q[3];
#pragma unroll
  for (int s = 0; s < 3; ++s)
    q[s] = fmaf(xs[s][0], xs[s][0],
           fmaf(xs[s][1], xs[s][1],
           fmaf(xs[s][2], xs[s][2], xs[s][3] * xs[s][3])));

  // ---- three independent 16-wide inclusive scans ----
  float i0 = q[0], i1 = q[1], i2 = q[2];
#pragma unroll
  for (int off = 1; off < LPP; off <<= 1) {
    const float t0 = __shfl_up(i0, off, LPP);
    const float t1 = __shfl_up(i1, off, LPP);
    const float t2 = __shfl_up(i2, off, LPP);
    if (sub >= off) { i0 += t0; i1 += t1; i2 += t2; }
  }
  const float T0 = __shfl(i0, LPP - 1, LPP);
  const float T1 = __shfl(i1, LPP - 1, LPP);
  const float T2 = __shfl(i2, LPP - 1, LPP);
  const float total = T0 + T1 + T2;                    // cs[192]
  const float E[3] = { i0 - q[0], T0 + i1 - q[1], T0 + T1 + i2 - q[2] };

  // ---- per-slot channel prefixes: p[s][k] = cs[64s + 4sub + k] ----
  float p[3][4];
#pragma unroll
  for (int s = 0; s < 3; ++s) {
    float run = E[s];
#pragma unroll
    for (int k = 0; k < 4; ++k) { p[s][k] = run; run = fmaf(xs[s][k], xs[s][k], run); }
  }

  // ---- head boundaries: hb0[s]=cs[64s+4sub-2], hb1[s]=cs[64s+4sub-1] ----
  float hb0[3], hb1[3];
#pragma unroll
  for (int s = 0; s < 3; ++s) {
    hb0[s] = __shfl_up(p[s][2], 1, LPP);
    hb1[s] = __shfl_up(p[s][3], 1, LPP);
  }
  const float B02 = __shfl(p[0][2], LPP - 1, LPP);   // cs[62]
  const float B03 = __shfl(p[0][3], LPP - 1, LPP);   // cs[63]
  const float B12 = __shfl(p[1][2], LPP - 1, LPP);   // cs[126]
  const float B13 = __shfl(p[1][3], LPP - 1, LPP);   // cs[127]
  if (sub == 0) {
    hb0[0] = 0.0f; hb1[0] = 0.0f;
    hb0[1] = B02;  hb1[1] = B03;
    hb0[2] = B12;  hb1[2] = B13;
  }

  // ---- gather cs[end], end = 2c+3 = 128s + 8sub + 2k + 3 (valid iff c <= 94) ----
  float ge0[4], ge1[4];
  {
    const float r00 = bperm(a0, p[0][3]), r01 = bperm(a0, p[1][3]);  // k=0
    const float r10 = bperm(a1, p[0][1]), r11 = bperm(a1, p[1][1]);  // k=1
    const float r20 = bperm(a1, p[0][3]), r21 = bperm(a1, p[1][3]);  // k=2
    const float r30 = bperm(a2, p[0][1]), r31 = bperm(a2, p[1][1]);  // k=3
    ge0[0] = (sub < 8) ? r00 : r01;
    ge0[1] = (sub < 8) ? r10 : r11;
    ge0[2] = (sub < 8) ? r20 : r21;
    ge0[3] = (sub < 7) ? r30 : r31;
    ge1[0] = bperm(a0, p[2][3]);
    ge1[1] = bperm(a1, p[2][1]);
    ge1[2] = bperm(a1, p[2][3]);
    ge1[3] = bperm(a2, p[2][1]);
  }

  // ---- windowed sums + series scale + coalesced NT stores ----
#pragma unroll
  for (int s = 0; s < 3; ++s) {
    float r[4];
#pragma unroll
    for (int k = 0; k < 4; ++k) {
      const float csh = (k >= 2) ? p[s][k - 2] : (k == 0 ? hb0[s] : hb1[s]);
      float cse;
      if (s == 0)      cse = ge0[k];
      else if (s == 1) cse = (4 * sub + k >= 31) ? total : ge1[k];
      else             cse = total;
      const float eps = (cse - csh) * AON;        // in [0, ~0.01]
      // (1+e)^-0.75 ~= 1 - 0.75e + 0.65625e^2 - 0.6015625e^3
      const float inv = fmaf(eps, fmaf(eps, fmaf(eps, -0.6015625f, 0.65625f), -0.75f), 1.0f);
      r[k] = xs[s][k] * inv;
    }
    nt_store4(r[0], r[1], r[2], r[3], &ob[16 * s + sub]);
  }
}

__global__ __launch_bounds__(BLOCK, 6) void lrn_kernel(
    const float* __restrict__ x, float* __restrict__ out, int npix) {
  const int tid  = threadIdx.x;
  const int lane = tid & 63;
  const int w    = tid >> 6;
  const int sub  = lane & 15;   // lane within pixel
  const int pl   = lane >> 4;   // pixel within wave

  const int slot   = blockIdx.x * WPB + w;   // wave-slot id
  const int nslots = gridDim.x * WPB;        // 6144
  const int ngrp   = (npix + PPW - 1) / PPW; // pixel-groups (50176)
  const int nit    = (ngrp - slot + nslots - 1) / nslots;  // 8 or 9
  if (nit <= 0) return;

  // bpermute byte addresses (lane-only; hoisted out of the loop)
  const int gb = lane & 48;
  const int a0 = (gb | ((2 * sub)     & 15)) << 2;
  const int a1 = (gb | ((2 * sub + 1) & 15)) << 2;
  const int a2 = (gb | ((2 * sub + 2) & 15)) << 2;

  const int nclamp = npix - 1;
  float4* const obase = (float4*)out;

  f32x4 A0, A1, A2, B0, B1, B2;

  // ---- prologue + peeled first iteration (no stores in flight yet) ----
  int gnext = slot;
  int fbA = fb_of(gnext, pl, sub, nclamp); gnext += nslots;
  issue3(x + (size_t)fbA * 4, A0, A1, A2);             // out: [La x3]
  int fbB = fb_of(gnext, pl, sub, nclamp); gnext += nslots;
  issue3(x + (size_t)fbB * 4, B0, B1, B2);             // out: [La x3, Lb x3]
  asm volatile("s_waitcnt vmcnt(3)" ::: "memory");     // La done, Lb in flight
  __builtin_amdgcn_sched_barrier(0);
  lrn_body(A0, A1, A2, obase + (fbA - sub), sub, a0, a1, a2);
  int done = 1;

  // ---- steady pairs: each wait releases the loads issued one full body earlier ----
  for (; done + 1 < nit; done += 2) {
    fbA = fb_of(gnext, pl, sub, nclamp); gnext += nslots;
    issue3(x + (size_t)fbA * 4, A0, A1, A2);           // out: [Lb, Sprev, La']
    asm volatile("s_waitcnt vmcnt(6)" ::: "memory");   // Lb done; La' + own stores pend
    __builtin_amdgcn_sched_barrier(0);
    lrn_body(B0, B1, B2, obase + (fbB - sub), sub, a0, a1, a2);

    fbB = fb_of(gnext, pl, sub, nclamp); gnext += nslots;
    issue3(x + (size_t)fbB * 4, B0, B1, B2);           // out: [La', Sb, Lb']
    asm volatile("s_waitcnt vmcnt(6)" ::: "memory");   // La' done
    __builtin_amdgcn_sched_barrier(0);
    lrn_body(A0, A1, A2, obase + (fbA - sub), sub, a0, a1, a2);
  }

  // ---- tail (odd nit): pending buffer is B ----
  if (done < nit) {
    asm volatile("s_waitcnt vmcnt(0)" ::: "memory");   // last iter: full drain is fine
    __builtin_amdgcn_sched_barrier(0);
    lrn_body(B0, B1, B2, obase + (fbB - sub), sub, a0, a1, a2);
  }

  asm volatile("s_waitcnt vmcnt(0)" ::: "memory");     // drain any dangling prefetch
}

extern "C" void kernel_launch(void* const* d_in, const int* in_sizes, int n_in,
                              void* d_out, int out_size, void* d_ws, size_t ws_size,
                              hipStream_t stream) {
  const float* x   = (const float*)d_in[0];
  float*       out = (float*)d_out;
  const int npix = in_sizes[0] / C;                  // 64*56*56 = 200704
  const int ngrp = (npix + PPW - 1) / PPW;           // 50176
  int grid = (ngrp + WPB - 1) / WPB;                 // cap for tiny inputs
  if (grid > GRID) grid = GRID;                      // 1536 -> 6144 slots, 8-9 iters
  lrn_kernel<<<grid, BLOCK, 0, stream>>>(x, out, npix);
}

// Round 7
// 264.179 us; speedup vs baseline: 1.0082x; 1.0019x over previous
//
#include <hip/hip_runtime.h>

// LRN (buggy-keras window) on x:(64,56,56,192) fp32 NHWC.
// window for channel c: [max(c-2,0), min(2c+3, C)); scale=(sum*2e-5+1)^0.75; out=x/scale
//
// R10: depth-2 ring pipeline, ALL VMEM in inline asm, stores never on the wait path.
// R9 (depth-1 forced prefetch) was null (93.9us, 2.46 TB/s) but confounded:
//  (a) depth-1 gives loads only ~600 cycles of slack vs ~1-1.5us queued latency;
//  (b) vmcnt retires IN ORDER and R9's waits had NT stores OLDER than the awaited
//      loads -> every wait also waited store retirement (NT = unknown latency);
//  (c) compiler-visible stores next to opaque asm can draw defensive vmcnt(0).
// R10: 3 register sets (A,B,C), issue L_{t+2} before body t -> 2 bodies + round-robin
// of slack per load; plain stores via asm (retire at TCC); wait ladder vmcnt(6)/(9)/
// steady (12) derived from in-order retirement: steady queue at the wait is
// [L_t, S_{t-2}, L_{t+1}, S_{t-1}, L_{t+2}] (15) and vmcnt(12) retires exactly L_t.
// GRID=1280 @ launch_bounds(256,5): 5 blocks/CU x 256 CU all resident, 20 waves/CU,
// steady ~6KB loads in flight per wave (~120KB/CU, 1.7x R9).
// Body = R5 (interleaved ownership, 3x16-wide scan, 12 bpermute gather);
// (1+e)^-0.75 via cubic series (e<=~0.01 -> err <1e-7 vs thr 0.108).

constexpr int   C     = 192;
constexpr int   LPP   = 16;             // lanes per pixel
constexpr int   PPW   = 4;              // pixels per wave per iteration
constexpr int   WPB   = 4;              // waves per block
constexpr int   BLOCK = 256;
constexpr int   GRID  = 1280;           // 5120 wave-slots; 5 blocks/CU, all resident
constexpr float AON   = 0.0001f / 5.0f; // alpha/n = 2e-5

typedef float f32x4 __attribute__((ext_vector_type(4)));

__device__ __forceinline__ float bperm(int byteaddr, float v) {
  return __int_as_float(__builtin_amdgcn_ds_bpermute(byteaddr, __float_as_int(v)));
}

// Issue 3 coalesced dwordx4 loads (bytes +0/+256/+512 from p) WITHOUT waiting.
__device__ __forceinline__ void issue3(const float* p, f32x4& d0, f32x4& d1, f32x4& d2) {
  asm volatile(
      "global_load_dwordx4 %0, %3, off\n\t"
      "global_load_dwordx4 %1, %3, off offset:256\n\t"
      "global_load_dwordx4 %2, %3, off offset:512"
      : "=&v"(d0), "=&v"(d1), "=&v"(d2)
      : "v"(p)
      : "memory");
}

// Issue 3 coalesced dwordx4 stores (bytes +0/+256/+512 from p) WITHOUT waiting.
// Plain stores (retire at TCC accept). Asm-opaque so the backend tracks no VMEM.
__device__ __forceinline__ void store3(float* p, f32x4 r0, f32x4 r1, f32x4 r2) {
  asm volatile(
      "global_store_dwordx4 %3, %0, off\n\t"
      "global_store_dwordx4 %3, %1, off offset:256\n\t"
      "global_store_dwordx4 %3, %2, off offset:512"
      :
      : "v"(r0), "v"(r1), "v"(r2), "v"(p)
      : "memory");
}

#define WAIT(N)                                        \
  do {                                                 \
    asm volatile("s_waitcnt vmcnt(" #N ")" ::: "memory"); \
    __builtin_amdgcn_sched_barrier(0);                 \
  } while (0)

__device__ __forceinline__ int fb_of(int g, int pl, int sub, int nclamp) {
  int p = g * PPW + pl;
  if (p > nclamp) p = nclamp;     // clamp: duplicate loads/stores of identical data
  return p * (C / 4) + sub;       // float4 index of this lane's slot-0 quad
}

// Compute one pixel-iteration from registers and store via store3.
// u0/u1/u2 = float4s {sub,16+sub,32+sub} of the pixel row; po = lane's slot-0 float addr.
__device__ __forceinline__ void lrn_body(const f32x4 u0, const f32x4 u1, const f32x4 u2,
                                         float* __restrict__ po, int sub,
                                         int a0, int a1, int a2) {
  float xs[3][4] = {{u0.x, u0.y, u0.z, u0.w},
                    {u1.x, u1.y, u1.z, u1.w},
                    {u2.x, u2.y, u2.z, u2.w}};

  // ---- chunk sums q[s] over slot s (chunk index m = 16s + sub) ----
  float q[3];
#pragma unroll
  for (int s = 0; s < 3; ++s)
    q[s] = fmaf(xs[s][0], xs[s][0],
           fmaf(xs[s][1], xs[s][1],
           fmaf(xs[s][2], xs[s][2], xs[s][3] * xs[s][3])));

  // ---- three independent 16-wide inclusive scans ----
  float i0 = q[0], i1 = q[1], i2 = q[2];
#pragma unroll
  for (int off = 1; off < LPP; off <<= 1) {
    const float t0 = __shfl_up(i0, off, LPP);
    const float t1 = __shfl_up(i1, off, LPP);
    const float t2 = __shfl_up(i2, off, LPP);
    if (sub >= off) { i0 += t0; i1 += t1; i2 += t2; }
  }
  const float T0 = __shfl(i0, LPP - 1, LPP);
  const float T1 = __shfl(i1, LPP - 1, LPP);
  const float T2 = __shfl(i2, LPP - 1, LPP);
  const float total = T0 + T1 + T2;                    // cs[192]
  const float E[3] = { i0 - q[0], T0 + i1 - q[1], T0 + T1 + i2 - q[2] };

  // ---- per-slot channel prefixes: p[s][k] = cs[64s + 4sub + k] ----
  float p[3][4];
#pragma unroll
  for (int s = 0; s < 3; ++s) {
    float run = E[s];
#pragma unroll
    for (int k = 0; k < 4; ++k) { p[s][k] = run; run = fmaf(xs[s][k], xs[s][k], run); }
  }

  // ---- head boundaries: hb0[s]=cs[64s+4sub-2], hb1[s]=cs[64s+4sub-1] ----
  float hb0[3], hb1[3];
#pragma unroll
  for (int s = 0; s < 3; ++s) {
    hb0[s] = __shfl_up(p[s][2], 1, LPP);
    hb1[s] = __shfl_up(p[s][3], 1, LPP);
  }
  const float B02 = __shfl(p[0][2], LPP - 1, LPP);   // cs[62]
  const float B03 = __shfl(p[0][3], LPP - 1, LPP);   // cs[63]
  const float B12 = __shfl(p[1][2], LPP - 1, LPP);   // cs[126]
  const float B13 = __shfl(p[1][3], LPP - 1, LPP);   // cs[127]
  if (sub == 0) {
    hb0[0] = 0.0f; hb1[0] = 0.0f;
    hb0[1] = B02;  hb1[1] = B03;
    hb0[2] = B12;  hb1[2] = B13;
  }

  // ---- gather cs[end], end = 2c+3 = 128s + 8sub + 2k + 3 (valid iff c <= 94) ----
  float ge0[4], ge1[4];
  {
    const float r00 = bperm(a0, p[0][3]), r01 = bperm(a0, p[1][3]);  // k=0
    const float r10 = bperm(a1, p[0][1]), r11 = bperm(a1, p[1][1]);  // k=1
    const float r20 = bperm(a1, p[0][3]), r21 = bperm(a1, p[1][3]);  // k=2
    const float r30 = bperm(a2, p[0][1]), r31 = bperm(a2, p[1][1]);  // k=3
    ge0[0] = (sub < 8) ? r00 : r01;
    ge0[1] = (sub < 8) ? r10 : r11;
    ge0[2] = (sub < 8) ? r20 : r21;
    ge0[3] = (sub < 7) ? r30 : r31;
    ge1[0] = bperm(a0, p[2][3]);
    ge1[1] = bperm(a1, p[2][1]);
    ge1[2] = bperm(a1, p[2][3]);
    ge1[3] = bperm(a2, p[2][1]);
  }

  // ---- windowed sums + series scale ----
  f32x4 R[3];
#pragma unroll
  for (int s = 0; s < 3; ++s) {
#pragma unroll
    for (int k = 0; k < 4; ++k) {
      const float csh = (k >= 2) ? p[s][k - 2] : (k == 0 ? hb0[s] : hb1[s]);
      float cse;
      if (s == 0)      cse = ge0[k];
      else if (s == 1) cse = (4 * sub + k >= 31) ? total : ge1[k];
      else             cse = total;
      const float eps = (cse - csh) * AON;        // in [0, ~0.01]
      // (1+e)^-0.75 ~= 1 - 0.75e + 0.65625e^2 - 0.6015625e^3
      const float inv = fmaf(eps, fmaf(eps, fmaf(eps, -0.6015625f, 0.65625f), -0.75f), 1.0f);
      R[s][k] = xs[s][k] * inv;
    }
  }
  store3(po, R[0], R[1], R[2]);
}

__global__ __launch_bounds__(BLOCK, 5) void lrn_kernel(
    const float* __restrict__ x, float* __restrict__ out, int npix) {
  const int tid  = threadIdx.x;
  const int lane = tid & 63;
  const int w    = tid >> 6;
  const int sub  = lane & 15;   // lane within pixel
  const int pl   = lane >> 4;   // pixel within wave

  const int slot   = blockIdx.x * WPB + w;   // wave-slot id
  const int ns     = gridDim.x * WPB;        // 5120
  const int ngrp   = (npix + PPW - 1) / PPW; // pixel-groups (50176)
  const int nit    = (ngrp - slot + ns - 1) / ns;  // 9 or 10
  if (nit <= 0) return;

  // bpermute byte addresses (lane-only; loop-invariant)
  const int gb = lane & 48;
  const int a0 = (gb | ((2 * sub)     & 15)) << 2;
  const int a1 = (gb | ((2 * sub + 1) & 15)) << 2;
  const int a2 = (gb | ((2 * sub + 2) & 15)) << 2;

  const int nclamp = npix - 1;

  f32x4 A0, A1, A2, B0, B1, B2, C0, C1, C2;  // ring sets 0,1,2

  int g = slot;  // body group for the upcoming iteration

  // ---- prologue: issue L0 (set A), L1 (set B) ----
  issue3(x + (size_t)fb_of(g,          pl, sub, nclamp) * 4, A0, A1, A2);
  issue3(x + (size_t)fb_of(g + ns,     pl, sub, nclamp) * 4, B0, B1, B2);

  // ---- it 0: issue L2 (set C); queue [L0 L1 L2]=9 -> wait 6 retires L0 ----
  issue3(x + (size_t)fb_of(g + 2 * ns, pl, sub, nclamp) * 4, C0, C1, C2);
  WAIT(6);
  lrn_body(A0, A1, A2, out + (size_t)fb_of(g, pl, sub, nclamp) * 4, sub, a0, a1, a2);
  g += ns;

  // ---- it 1: issue L3 (set A); queue [L1 L2 S0 L3]=12 -> wait 9 retires L1 ----
  if (nit > 1) {
    issue3(x + (size_t)fb_of(g + 2 * ns, pl, sub, nclamp) * 4, A0, A1, A2);
    WAIT(9);
    lrn_body(B0, B1, B2, out + (size_t)fb_of(g, pl, sub, nclamp) * 4, sub, a0, a1, a2);
    g += ns;
  }

  // ---- steady: it t>=2. queue [L_t S_{t-2} L_{t+1} S_{t-1} L_{t+2}]=15 ->
  //      wait 12 retires exactly L_t (oldest); never blocks on stores. ----
  for (int t = 2; t < nit; t += 3) {
    issue3(x + (size_t)fb_of(g + 2 * ns, pl, sub, nclamp) * 4, B0, B1, B2);
    WAIT(12);
    lrn_body(C0, C1, C2, out + (size_t)fb_of(g, pl, sub, nclamp) * 4, sub, a0, a1, a2);
    g += ns;
    if (t + 1 < nit) {
      issue3(x + (size_t)fb_of(g + 2 * ns, pl, sub, nclamp) * 4, C0, C1, C2);
      WAIT(12);
      lrn_body(A0, A1, A2, out + (size_t)fb_of(g, pl, sub, nclamp) * 4, sub, a0, a1, a2);
      g += ns;
      if (t + 2 < nit) {
        issue3(x + (size_t)fb_of(g + 2 * ns, pl, sub, nclamp) * 4, A0, A1, A2);
        WAIT(12);
        lrn_body(B0, B1, B2, out + (size_t)fb_of(g, pl, sub, nclamp) * 4, sub, a0, a1, a2);
        g += ns;
      }
    }
  }

  asm volatile("s_waitcnt vmcnt(0)" ::: "memory");  // drain dangling clamped prefetch
}

extern "C" void kernel_launch(void* const* d_in, const int* in_sizes, int n_in,
                              void* d_out, int out_size, void* d_ws, size_t ws_size,
                              hipStream_t stream) {
  const float* x   = (const float*)d_in[0];
  float*       out = (float*)d_out;
  const int npix = in_sizes[0] / C;                  // 64*56*56 = 200704
  const int ngrp = (npix + PPW - 1) / PPW;           // 50176
  int grid = (ngrp + WPB - 1) / WPB;                 // cap for tiny inputs
  if (grid > GRID) grid = GRID;                      // 1280 -> 5120 slots, 9-10 iters
  lrn_kernel<<<grid, BLOCK, 0, stream>>>(x, out, npix);
}